// Round 5
// baseline (45.401 us; speedup 1.0000x reference)
//
#include <hip/hip_runtime.h>

// ---------- types ----------
using f32x4  = __attribute__((ext_vector_type(4))) float;
using bf16x8 = __attribute__((ext_vector_type(8))) short;   // 8 bf16 in 4 VGPRs

__device__ __forceinline__ unsigned short f2bf(float f) {
    union { float f; unsigned int u; } v; v.f = f;
    unsigned int r = v.u + 0x7fffu + ((v.u >> 16) & 1u);  // RNE
    return (unsigned short)(r >> 16);
}

__device__ __forceinline__ float bf2f(unsigned short u) {
    union { unsigned int u; float f; } v; v.u = ((unsigned int)u) << 16;
    return v.f;
}

// ---------- transpose D [16][256c][256q] f32 -> Dt [16][256q][256c] bf16; zero stats ----------
__global__ __launch_bounds__(256) void transposeD(
    const float* __restrict__ x, unsigned short* __restrict__ y, float* __restrict__ stats) {
    __shared__ float tile[32][33];
    int b  = blockIdx.z;
    int p0 = blockIdx.x * 32;      // q tile
    int c0 = blockIdx.y * 32;      // c tile
    const float* xb = x + (size_t)b * 256 * 256;
    unsigned short* yb = y + (size_t)b * 256 * 256;
    int tx = threadIdx.x, ty = threadIdx.y;
    #pragma unroll
    for (int i = 0; i < 32; i += 8)
        tile[ty + i][tx] = xb[(size_t)(c0 + ty + i) * 256 + (p0 + tx)];
    __syncthreads();
    int tid = ty * 32 + tx;
    #pragma unroll
    for (int k = 0; k < 2; ++k) {
        int wi = tid * 2 + k;          // 0..511
        int pl = wi >> 4;              // local q row
        int cp = wi & 15;              // c-pair
        unsigned short lo = f2bf(tile[2 * cp][pl]);
        unsigned short hi = f2bf(tile[2 * cp + 1][pl]);
        unsigned int packed = (unsigned int)lo | ((unsigned int)hi << 16);
        *reinterpret_cast<unsigned int*>(&yb[(size_t)(p0 + pl) * 256 + (c0 + 2 * cp)]) = packed;
    }
    if (blockIdx.x == 0 && blockIdx.y == 0 && blockIdx.z == 0 && tid == 0) {
        stats[0] = 0.f;
        stats[1] = 0.f;
    }
}

// ---------- fused conv: stage S->LDS(bf16,swizzled), GEMM vs Dt, partials to P ----------
// Block = (b, image row r). Computes G[p=r*64 .. r*64+64)[q=0..256) and writes
// 16-tap diagonal sums NON-ATOMICALLY to P[b][r][i][x].
//
// LDS A layout (bf16, XOR-swizzled for conflict-free ds_read_b128 / ds_write_b64):
//   byte(p, c) = p*512 + (((c>>3) ^ (p&15) ^ (p>>4)) << 4) + (c&7)*2
// Epilogue layout gtT[q][p]: stride 68 bf16 (136 B) -> b64 dump writes (4 t-values
// contiguous in p), 8B-aligned for all q; gather reads columns.
__global__ __launch_bounds__(256, 4) void conv_fused(
    const float* __restrict__ S,             // [16][256][64][64] f32
    const unsigned short* __restrict__ Dt,   // [16][256q][256c] bf16
    float* __restrict__ P) {                 // [16][64][16][52] f32 partials
    // union: At swizzled bf16 (32768 B)  /  gtT bf16 [256][68] (34816 B)
    __shared__ __align__(16) char lds[256 * 68 * 2];
    char* base = lds;

    int b = blockIdx.x >> 6;
    int r = blockIdx.x & 63;
    int tid = threadIdx.x;

    int w    = tid >> 6;          // wave 0..3
    int lane = tid & 63;
    int m    = lane & 15;
    int kg   = lane >> 4;
    const unsigned short* Db = Dt + ((size_t)(b * 256 + 64 * w)) * 256;

    // ---- stage: issue ALL 16 global loads (non-temporal: bypass MALL-hit path) ----
    // thread t: px = t&15 (p-group 4*px..4*px+3), cq = t>>4 (c-group 4*cq..4*cq+3 per round)
    int px = tid & 15;
    int cq = tid >> 4;
    const float* Sbr = S + ((size_t)b * 256 * 64 + r) * 64;   // + c*4096 + p

    f32x4 v[4][4];
    #pragma unroll
    for (int rho = 0; rho < 4; ++rho) {
        int c0 = rho * 64 + 4 * cq;
        #pragma unroll
        for (int j = 0; j < 4; ++j)
            v[rho][j] = __builtin_nontemporal_load(
                reinterpret_cast<const f32x4*>(Sbr + (size_t)(c0 + j) * 4096 + 4 * px));
    }
    // prefetch B for K-step 0 (stays in flight across the lgkm-only barrier)
    bf16x8 bcur[4];
    #pragma unroll
    for (int n = 0; n < 4; ++n)
        bcur[n] = *reinterpret_cast<const bf16x8*>(Db + (size_t)(16 * n + m) * 256 + kg * 8);
    __builtin_amdgcn_sched_barrier(0);   // keep all loads issued before any consumption

    // convert + in-register 4x4 transpose + ds_write_b64
    #pragma unroll
    for (int rho = 0; rho < 4; ++rho) {
        int slot = 8 * rho + (cq >> 1);
        int half = cq & 1;
        #pragma unroll
        for (int e = 0; e < 4; ++e) {
            int p = 4 * px + e;
            int swz = (p & 15) ^ (p >> 4);
            ushort4 o;
            o.x = f2bf(v[rho][0][e]);
            o.y = f2bf(v[rho][1][e]);
            o.z = f2bf(v[rho][2][e]);
            o.w = f2bf(v[rho][3][e]);
            *reinterpret_cast<ushort4*>(base + p * 512 + ((slot ^ swz) << 4) + half * 8) = o;
        }
    }
    // barrier that waits only for LDS writes; B-prefetch (vmcnt) stays in flight
    asm volatile("s_waitcnt lgkmcnt(0)" ::: "memory");
    __builtin_amdgcn_s_barrier();

    // ---- GEMM: wave w computes q in [64w, 64w+64), all 64 p rows, K=256 ----
    f32x4 acc[4][4];
    #pragma unroll
    for (int i = 0; i < 4; ++i)
        #pragma unroll
        for (int j = 0; j < 4; ++j)
            acc[i][j] = f32x4{0.f, 0.f, 0.f, 0.f};

    #pragma unroll
    for (int step = 0; step < 8; ++step) {
        bf16x8 bnext[4];
        if (step < 7) {
            #pragma unroll
            for (int n = 0; n < 4; ++n)
                bnext[n] = *reinterpret_cast<const bf16x8*>(
                    Db + (size_t)(16 * n + m) * 256 + (step + 1) * 32 + kg * 8);
        }
        bf16x8 af[4];
        #pragma unroll
        for (int pa = 0; pa < 4; ++pa) {
            int p = 16 * pa + m;
            int slot = (4 * step + kg) ^ m ^ pa;     // (c>>3) ^ (p&15) ^ (p>>4)
            af[pa] = *reinterpret_cast<const bf16x8*>(base + p * 512 + (slot << 4));
        }
        #pragma unroll
        for (int pa = 0; pa < 4; ++pa)
            #pragma unroll
            for (int n = 0; n < 4; ++n)
                acc[pa][n] = __builtin_amdgcn_mfma_f32_16x16x32_bf16(af[pa], bcur[n], acc[pa][n], 0, 0, 0);
        #pragma unroll
        for (int n = 0; n < 4; ++n)
            bcur[n] = bnext[n];
    }

    __syncthreads();   // all waves done reading At before overwrite

    // ---- dump G tile to LDS as bf16: gtT[q][p], stride 68, b64-packed writes ----
    unsigned short* gt = (unsigned short*)base;
    #pragma unroll
    for (int pa = 0; pa < 4; ++pa) {
        int p0 = 16 * pa + 4 * kg;
        #pragma unroll
        for (int n = 0; n < 4; ++n) {
            int q = 64 * w + 16 * n + m;
            ushort4 o;
            o.x = f2bf(acc[pa][n][0]);
            o.y = f2bf(acc[pa][n][1]);
            o.z = f2bf(acc[pa][n][2]);
            o.w = f2bf(acc[pa][n][3]);
            *reinterpret_cast<ushort4*>(&gt[q * 68 + p0]) = o;
        }
    }
    __syncthreads();

    // ---- partials: P[b][r][i][x] = sum_j G[x+j][16i+j] = sum_j gtT[16i+j][x+j] ----
    int ilo = (r > 48) ? (r - 48) : 0;
    int ihi = (r < 15) ? r : 15;
    int total = (ihi - ilo + 1) * 49;
    for (int o = tid; o < total; o += 256) {
        int i = ilo + o / 49;
        int x = o % 49;
        float s = 0.f;
        int qb = 16 * i;
        #pragma unroll
        for (int j = 0; j < 16; ++j)
            s += bf2f(gt[(qb + j) * 68 + (x + j)]);
        P[((size_t)((b * 64 + r) * 16 + i)) * 52 + x] = s;
    }
}

// ---------- reduce partials + global stats: mm[b][y][x] = sum_i P[b][y+i][i][x] ----------
__global__ __launch_bounds__(256) void reduce_kernel(
    const float* __restrict__ P, float* __restrict__ mm, float* __restrict__ stats) {
    int idx = blockIdx.x * 256 + threadIdx.x;
    float s = 0.f;
    if (idx < 38416) {
        int b  = idx / 2401;
        int yx = idx % 2401;
        int y  = yx / 49;
        int x  = yx % 49;
        #pragma unroll
        for (int i = 0; i < 16; ++i)
            s += P[((size_t)((b * 64 + y + i) * 16 + i)) * 52 + x];
        mm[idx] = s;
    }
    // block-reduce (sum, sumsq), one atomic pair per block
    __shared__ float rs[256];
    __shared__ float rq[256];
    int tid = threadIdx.x;
    rs[tid] = (idx < 38416) ? s : 0.f;
    rq[tid] = (idx < 38416) ? s * s : 0.f;
    __syncthreads();
    for (int st = 128; st > 0; st >>= 1) {
        if (tid < st) { rs[tid] += rs[tid + st]; rq[tid] += rq[tid + st]; }
        __syncthreads();
    }
    if (tid == 0) {
        atomicAdd(&stats[0], rs[0]);
        atomicAdd(&stats[1], rq[0]);
    }
}

// ---------- fallback naive conv (tiny ws) ----------
__global__ __launch_bounds__(256) void conv_naive(
    const float* __restrict__ S, const float* __restrict__ D, float* __restrict__ mm) {
    int blk = blockIdx.x;            // b*2401 + y*49 + x
    int b = blk / 2401;
    int yx = blk % 2401;
    int y = yx / 49, x = yx % 49;
    int c = threadIdx.x;
    const float* Sp = S + (((size_t)b * 256 + c) * 64 + y) * 64 + x;
    const float* Dp = D + ((size_t)b * 256 + c) * 256;
    float s = 0.f;
    #pragma unroll
    for (int i = 0; i < 16; ++i)
        #pragma unroll 4
        for (int j = 0; j < 16; ++j)
            s += Sp[i * 64 + j] * Dp[i * 16 + j];
    __shared__ float red[256];
    red[c] = s;
    __syncthreads();
    for (int st = 128; st > 0; st >>= 1) {
        if (c < st) red[c] += red[c + st];
        __syncthreads();
    }
    if (c == 0) mm[blk] = red[0];
}

// ---------- fallback stats: raw sums over 38416 values ----------
__global__ __launch_bounds__(1024) void stats_kernel(
    const float* __restrict__ mm, float* __restrict__ stats) {
    __shared__ float ssum[1024];
    __shared__ float ssq[1024];
    int tid = threadIdx.x;
    float s = 0.f, q = 0.f;
    for (int i = tid; i < 38416; i += 1024) {
        float v = mm[i];
        s += v; q += v * v;
    }
    ssum[tid] = s; ssq[tid] = q;
    __syncthreads();
    for (int st = 512; st > 0; st >>= 1) {
        if (tid < st) { ssum[tid] += ssum[tid + st]; ssq[tid] += ssq[tid + st]; }
        __syncthreads();
    }
    if (tid == 0) {
        stats[0] = ssum[0];
        stats[1] = ssq[0];
    }
}

// ---------- normalize + bilinear 49x49 -> 256x256 (stats are raw sums) ----------
__global__ __launch_bounds__(256) void bilinear_kernel(
    const float* __restrict__ mm, const float* __restrict__ stats,
    const float* __restrict__ gamma, const float* __restrict__ beta,
    float* __restrict__ out) {
    int idx = blockIdx.x * 256 + threadIdx.x;   // 16*256*256 = 1,048,576
    int b  = idx >> 16;
    int oy = (idx >> 8) & 255;
    int ox = idx & 255;
    const float scale = 49.0f / 256.0f;
    float cy = fminf(fmaxf((oy + 0.5f) * scale - 0.5f, 0.0f), 48.0f);
    int y0 = (int)cy; int y1 = min(y0 + 1, 48); float wy = cy - (float)y0;
    float cx = fminf(fmaxf((ox + 0.5f) * scale - 0.5f, 0.0f), 48.0f);
    int x0 = (int)cx; int x1 = min(x0 + 1, 48); float wx = cx - (float)x0;
    const float* mb = mm + (size_t)b * 2401;
    float v00 = mb[y0 * 49 + x0];
    float v01 = mb[y0 * 49 + x1];
    float v10 = mb[y1 * 49 + x0];
    float v11 = mb[y1 * 49 + x1];
    float r0 = v00 * (1.f - wy) + v10 * wy;
    float r1 = v01 * (1.f - wy) + v11 * wy;
    float v  = r0 * (1.f - wx) + r1 * wx;
    const float invN = 1.0f / 38416.0f;
    float mean = stats[0] * invN;
    float var  = stats[1] * invN - mean * mean;
    float rstd = rsqrtf(var + 1e-5f);
    v = (v - mean) * rstd * gamma[0] + beta[0];
    out[idx] = v;
}

extern "C" void kernel_launch(void* const* d_in, const int* in_sizes, int n_in,
                              void* d_out, int out_size, void* d_ws, size_t ws_size,
                              hipStream_t stream) {
    const float* S     = (const float*)d_in[0];   // (16,256,64,64)
    const float* D     = (const float*)d_in[1];   // (16,256,16,16)
    const float* gamma = (const float*)d_in[2];   // (1,)
    const float* beta  = (const float*)d_in[3];   // (1,)
    float* out = (float*)d_out;                   // (16,1,256,256)

    char* ws = (char*)d_ws;
    const size_t sizeDt = (size_t)16 * 256 * 256 * 2;        // 2,097,152
    const size_t sizeMm = (size_t)38416 * 4;                 //   153,664
    const size_t sizeP  = (size_t)16 * 64 * 16 * 52 * 4;     // 3,407,872
    const size_t offDt = 0;
    const size_t offMm = offDt + sizeDt;
    const size_t offStats = offMm + sizeMm;
    const size_t offP = (offStats + 2 * sizeof(float) + 255) & ~(size_t)255;
    const size_t needFast = offP + sizeP;

    bool fast = (ws_size >= needFast);
    float* mm;
    float* stats;
    if (fast) {
        mm    = (float*)(ws + offMm);
        stats = (float*)(ws + offStats);
    } else {
        mm    = (float*)ws;
        stats = (float*)(ws + sizeMm);
    }

    if (fast) {
        unsigned short* Dt = (unsigned short*)(ws + offDt);
        float* P = (float*)(ws + offP);
        transposeD<<<dim3(8, 8, 16), dim3(32, 8), 0, stream>>>(D, Dt, stats);
        conv_fused<<<1024, 256, 0, stream>>>(S, Dt, P);
        reduce_kernel<<<151, 256, 0, stream>>>(P, mm, stats);
    } else {
        conv_naive<<<16 * 2401, 256, 0, stream>>>(S, D, mm);
        stats_kernel<<<1, 1024, 0, stream>>>(mm, stats);
    }
    bilinear_kernel<<<4096, 256, 0, stream>>>(mm, stats, gamma, beta, out);
}